// Round 16
// baseline (361.415 us; speedup 1.0000x reference)
//
#include <hip/hip_runtime.h>
#include <math.h>

#define N_EMBD    1024
#define N_HEAD    16
#define HEAD_SIZE 64
#define T_SEQ     2048
#define BATCH     2
#define HIDDEN    2048
#define ROWS      4096

typedef __attribute__((ext_vector_type(8))) short bf16x8;
typedef __attribute__((ext_vector_type(4))) float f32x4;
typedef __attribute__((ext_vector_type(16))) float f32x16;
typedef unsigned short u16;

__device__ __forceinline__ u16 f2bf(float x) {
    union { float f; unsigned u; } v; v.f = x;
    unsigned r = v.u + 0x7fffu + ((v.u >> 16) & 1u);
    return (u16)(r >> 16);
}
__device__ __forceinline__ float bf2f(u16 h) {
    union { unsigned u; float f; } v; v.u = ((unsigned)h) << 16;
    return v.f;
}
__device__ __forceinline__ unsigned cvtpk_bf16(float lo, float hi) {
    unsigned r;
    asm volatile("v_cvt_pk_bf16_f32 %0, %1, %2" : "=v"(r) : "v"(lo), "v"(hi));
    return r;
}
__device__ __forceinline__ void gload16(const void* g, void* lds) {
    __builtin_amdgcn_global_load_lds((const __attribute__((address_space(1))) void*)g,
                                     (__attribute__((address_space(3))) void*)lds, 16, 0, 0);
}

// ================= weight transpose + bf16 cast (single fused kernel) =================
__device__ __forceinline__ void wtrans_body(const float* s, u16* d, int ldS, int ldD,
                                            int k0, int n0, float Ts[64][65])
{
    const int tid = threadIdx.x;
    const int rr = tid >> 4, c4 = (tid & 15) * 4;
#pragma unroll
    for (int i = 0; i < 4; i++) {
        float4 v = *(const float4*)(s + (size_t)(k0 + rr + i * 16) * ldS + n0 + c4);
        Ts[rr + i * 16][c4 + 0] = v.x;
        Ts[rr + i * 16][c4 + 1] = v.y;
        Ts[rr + i * 16][c4 + 2] = v.z;
        Ts[rr + i * 16][c4 + 3] = v.w;
    }
    __syncthreads();
    const int nr = tid >> 2, kc = (tid & 3) * 16;
#pragma unroll
    for (int j = 0; j < 4; j++) {
        u16 t0 = f2bf(Ts[kc + j * 4 + 0][nr]);
        u16 t1 = f2bf(Ts[kc + j * 4 + 1][nr]);
        u16 t2 = f2bf(Ts[kc + j * 4 + 2][nr]);
        u16 t3 = f2bf(Ts[kc + j * 4 + 3][nr]);
        *(ushort4*)(d + (size_t)(n0 + nr) * ldD + k0 + kc + j * 4) = make_ushort4(t0, t1, t2, t3);
    }
}

// linear blocks: [0,768) qkv heads; [768,1792) w_w/v_w; [1792,2048) proj; [2048,2560) p_w
__global__ __launch_bounds__(256) void wtrans_all(const float* __restrict__ Wq, const float* __restrict__ Wk,
                                                  const float* __restrict__ Wv, const float* __restrict__ ww,
                                                  const float* __restrict__ vv, const float* __restrict__ pw,
                                                  const float* __restrict__ ppw,
                                                  u16* __restrict__ Wqkv, u16* __restrict__ wwT,
                                                  u16* __restrict__ vvT, u16* __restrict__ pwT,
                                                  u16* __restrict__ ppT)
{
    __shared__ float Ts[64][65];
    const int b = blockIdx.x;
    const float* s; u16* d; int ldS, ldD, k0, n0;
    if (b < 768) {
        const int z = b >> 4;
        k0 = (b & 15) * 64; n0 = 0;
        const int which = z >> 4;
        s = (which == 0 ? Wq : which == 1 ? Wk : Wv) + (size_t)(z & 15) * 65536;
        d = Wqkv + (size_t)z * 65536;
        ldS = 64; ldD = 1024;
    } else if (b < 1792) {
        const int b2 = b - 768, z = b2 >> 4;
        k0 = (b2 & 15) * 64; n0 = (z & 31) * 64;
        s = (z >> 5) ? vv : ww; d = (z >> 5) ? vvT : wwT;
        ldS = 2048; ldD = 1024;
    } else if (b < 2048) {
        const int b3 = b - 1792;
        k0 = (b3 & 15) * 64; n0 = (b3 >> 4) * 64;
        s = pw; d = pwT; ldS = 1024; ldD = 1024;
    } else {
        const int b4 = b - 2048;
        k0 = (b4 & 31) * 64; n0 = (b4 >> 5) * 64;
        s = ppw; d = ppT; ldS = 1024; ldD = 2048;
    }
    wtrans_body(s, d, ldS, ldD, k0, n0, Ts);
}

// ================= LayerNorm f32 -> bf16 =================
__global__ __launch_bounds__(256) void ln_kernel(const float* __restrict__ x,
                                                 const float* __restrict__ w,
                                                 const float* __restrict__ b,
                                                 u16* __restrict__ out)
{
    const int row = blockIdx.x;
    const int tid = threadIdx.x;
    const float* xr = x + (size_t)row * N_EMBD;
    float4 v = *(const float4*)(xr + tid * 4);
    float s  = v.x + v.y + v.z + v.w;
    float s2 = v.x*v.x + v.y*v.y + v.z*v.z + v.w*v.w;
#pragma unroll
    for (int off = 32; off; off >>= 1) {
        s  += __shfl_xor(s, off);
        s2 += __shfl_xor(s2, off);
    }
    __shared__ float ss[4], ss2[4];
    if ((tid & 63) == 0) { ss[tid >> 6] = s; ss2[tid >> 6] = s2; }
    __syncthreads();
    s  = ss[0] + ss[1] + ss[2] + ss[3];
    s2 = ss2[0] + ss2[1] + ss2[2] + ss2[3];
    const float mean = s * (1.0f / N_EMBD);
    const float var  = s2 * (1.0f / N_EMBD) - mean * mean;
    const float rstd = rsqrtf(var + 1e-5f);
    float4 wv = *(const float4*)(w + tid * 4);
    float4 bv = *(const float4*)(b + tid * 4);
    ushort4 st = make_ushort4(f2bf((v.x - mean) * rstd * wv.x + bv.x),
                              f2bf((v.y - mean) * rstd * wv.y + bv.y),
                              f2bf((v.z - mean) * rstd * wv.z + bv.z),
                              f2bf((v.w - mean) * rstd * wv.w + bv.w));
    *(ushort4*)(out + (size_t)row * N_EMBD + tid * 4) = st;
}

// ================= RoPE on bf16 q,k; q additionally pre-scaled by qs = log2(e)/8 =================
__global__ __launch_bounds__(256) void rope_kernel(u16* __restrict__ q, u16* __restrict__ k)
{
    const int u = blockIdx.x * 256 + threadIdx.x;
    const int i  = u & 31;
    const int t  = (u >> 5) & (T_SEQ - 1);
    const int bh = u >> 16;
    const size_t base = ((size_t)bh * T_SEQ + t) * HEAD_SIZE + 2 * i;
    const float L = 0.28782313662425572f;   // ln(10000)/32
    const float QS = 0.125f * 1.44269504088896f;   // 1/sqrt(64) * log2(e)
    const int i0 = (2 * i) & 31, i1 = (2 * i + 1) & 31;
    float c0, s0, c1, s1;
    sincosf((float)t * __expf(-(float)i0 * L), &s0, &c0);
    sincosf((float)t * __expf(-(float)i1 * L), &s1, &c1);
    float a0 = bf2f(q[base]), a1 = bf2f(q[base + 1]);
    q[base]     = f2bf((a0 * c0 - a1 * s0) * QS);
    q[base + 1] = f2bf((a1 * c1 + a0 * s1) * QS);
    float b0 = bf2f(k[base]), b1 = bf2f(k[base + 1]);
    k[base]     = f2bf(b0 * c0 - b1 * s0);
    k[base + 1] = f2bf(b1 * c1 + b0 * s1);
}

// ================= MFMA GEMM (128x64 tile, BK=64 swizzled, 2-phase dbuf) — r12-measured best ====
__global__ __launch_bounds__(256) void gemm_br(const u16* __restrict__ A, const u16* __restrict__ Bt,
                                               const float* __restrict__ bias, const float* __restrict__ resid,
                                               float* __restrict__ Cf,
                                               int N, int K)
{
    __shared__ __align__(16) u16 As[2][128 * 64];
    __shared__ __align__(16) u16 Bs[2][64 * 64];
    const int tid = threadIdx.x, w = tid >> 6, l = tid & 63, l15 = l & 15, l4 = l >> 4;
    const int wm = w >> 1, wn = w & 1;
    const int n0 = blockIdx.x * 64, m0 = blockIdx.y * 128;
    f32x4 acc[4][2] = {};
    const int NT = K >> 6;

    auto stage = [&](int buf, int k0) {
#pragma unroll
        for (int c = 0; c < 4; c++) {
            const int slot = c * 256 + tid;
            const int row = slot >> 3;
            const int sw = ((slot & 7) * 16) ^ ((row & 7) << 4);
            gload16((const char*)(A + (size_t)(m0 + row) * K + k0) + sw, (char*)&As[buf][0] + slot * 16);
        }
#pragma unroll
        for (int c = 0; c < 2; c++) {
            const int slot = c * 256 + tid;
            const int row = slot >> 3;
            const int sw = ((slot & 7) * 16) ^ ((row & 7) << 4);
            gload16((const char*)(Bt + (size_t)(n0 + row) * K + k0) + sw, (char*)&Bs[buf][0] + slot * 16);
        }
    };

    stage(0, 0);
    __syncthreads();
    int cur = 0;
    for (int t = 0; t < NT; t++) {
        if (t + 1 < NT) stage(cur ^ 1, (t + 1) << 6);
#pragma unroll
        for (int ks = 0; ks < 2; ks++) {
            const int cb = ks * 64 + l4 * 16;
            bf16x8 af[4], bf[2];
#pragma unroll
            for (int mt = 0; mt < 4; mt++) {
                const int row = wm * 64 + mt * 16 + l15;
                af[mt] = *(const bf16x8*)((const char*)&As[cur][0] + row * 128 + (cb ^ ((row & 7) << 4)));
            }
#pragma unroll
            for (int u = 0; u < 2; u++) {
                const int row = wn * 32 + u * 16 + l15;
                bf[u] = *(const bf16x8*)((const char*)&Bs[cur][0] + row * 128 + (cb ^ ((row & 7) << 4)));
            }
#pragma unroll
            for (int mt = 0; mt < 4; mt++)
#pragma unroll
                for (int u = 0; u < 2; u++)
                    acc[mt][u] = __builtin_amdgcn_mfma_f32_16x16x32_bf16(af[mt], bf[u], acc[mt][u], 0, 0, 0);
        }
        __syncthreads();
        cur ^= 1;
    }
#pragma unroll
    for (int mt = 0; mt < 4; mt++) {
#pragma unroll
        for (int u = 0; u < 2; u++) {
            const int n = n0 + wn * 32 + u * 16 + l15;
            const float bi = bias[n];
#pragma unroll
            for (int r = 0; r < 4; r++) {
                const int m = m0 + wm * 64 + mt * 16 + l4 * 4 + r;
                const size_t idx = (size_t)m * N + n;
                Cf[idx] = acc[mt][u][r] + bi + resid[idx];
            }
        }
    }
}

// ================= QKV GEMM (128x128, packed BK=32, 2-phase dbuf) =================
__global__ __launch_bounds__(256, 4) void gemm_qkv(const u16* __restrict__ A, const u16* __restrict__ Bt,
                                                   u16* __restrict__ qo, u16* __restrict__ ko, u16* __restrict__ vto)
{
    __shared__ __align__(16) u16 As[2][64 * 64];   // packed [64][128B]
    __shared__ __align__(16) u16 Bs[2][64 * 64];
    const int tid = threadIdx.x, w = tid >> 6, l = tid & 63, l15 = l & 15, l4 = l >> 4;
    const int wm = w >> 1, wn = w & 1;
    const int n0 = blockIdx.x * 128, m0 = blockIdx.y * 128;
    const int K = N_EMBD;
    f32x4 acc[4][4] = {};
    const int NT = K >> 5;

    auto stage = [&](int buf, int k0) {
#pragma unroll
        for (int c = 0; c < 2; c++) {
            const int slot = c * 256 + tid;
            const int r2 = slot >> 3;
            const int w16u = (slot & 7) ^ (r2 & 7);
            const int grow = (w16u >> 2) * 64 + r2;
            const int kc = w16u & 3;
            gload16(A  + (size_t)(m0 + grow) * K + k0 + kc * 8, (char*)&As[buf][0] + slot * 16);
            gload16(Bt + (size_t)(n0 + grow) * K + k0 + kc * 8, (char*)&Bs[buf][0] + slot * 16);
        }
    };

    stage(0, 0);
    __syncthreads();
    int cur = 0;
    for (int t = 0; t < NT; t++) {
        if (t + 1 < NT) stage(cur ^ 1, (t + 1) << 5);
        bf16x8 af[4], bf[4];
#pragma unroll
        for (int q4 = 0; q4 < 4; q4++) {
            const int ga = wm * 64 + q4 * 16 + l15;
            const int ra = ga & 63, ha = ga >> 6;
            af[q4] = *(const bf16x8*)((const char*)&As[cur][0] + ra * 128 + (((ha << 2) | l4) ^ (ra & 7)) * 16);
            const int gb = wn * 64 + q4 * 16 + l15;
            const int rb = gb & 63, hb = gb >> 6;
            bf[q4] = *(const bf16x8*)((const char*)&Bs[cur][0] + rb * 128 + (((hb << 2) | l4) ^ (rb & 7)) * 16);
        }
#pragma unroll
        for (int mt = 0; mt < 4; mt++)
#pragma unroll
            for (int nt = 0; nt < 4; nt++)
                acc[mt][nt] = __builtin_amdgcn_mfma_f32_16x16x32_bf16(af[mt], bf[nt], acc[mt][nt], 0, 0, 0);
        __syncthreads();
        cur ^= 1;
    }
#pragma unroll
    for (int mt = 0; mt < 4; mt++) {
#pragma unroll
        for (int nt = 0; nt < 4; nt++) {
            const int n = n0 + wn * 64 + nt * 16 + l15;
            const int which = n >> 10, hd = (n >> 6) & 15, dd = n & 63;
            const int mb = m0 + wm * 64 + mt * 16 + l4 * 4;
            const int bI = mb >> 11, tq = mb & (T_SEQ - 1);
            if (which == 2) {
                ushort4 st = make_ushort4(f2bf(acc[mt][nt][0]), f2bf(acc[mt][nt][1]),
                                          f2bf(acc[mt][nt][2]), f2bf(acc[mt][nt][3]));
                *(ushort4*)(vto + ((size_t)(bI * N_HEAD + hd) * HEAD_SIZE + dd) * T_SEQ + tq) = st;
            } else {
                u16* dst = (which == 0) ? qo : ko;
#pragma unroll
                for (int r = 0; r < 4; r++)
                    dst[((size_t)(bI * N_HEAD + hd) * T_SEQ + tq + r) * HEAD_SIZE + dd] = f2bf(acc[mt][nt][r]);
            }
        }
    }
}

// ================= Fused dual-GEMM GLU (128x64, packed BK=32, 4 blocks/CU) =================
__global__ __launch_bounds__(256, 4) void gemm_glu(const u16* __restrict__ A, const u16* __restrict__ Bw,
                                                   const u16* __restrict__ Bv,
                                                   const float* __restrict__ wb, const float* __restrict__ vb,
                                                   u16* __restrict__ G)
{
    __shared__ __align__(16) u16 As[2][64 * 64];
    __shared__ __align__(16) u16 Bws[2][32 * 64];
    __shared__ __align__(16) u16 Bvs[2][32 * 64];
    const int tid = threadIdx.x, w = tid >> 6, l = tid & 63, l15 = l & 15, l4 = l >> 4;
    const int wm = w >> 1, wn = w & 1;
    const int n0 = blockIdx.x * 64, m0 = blockIdx.y * 128;
    const int K = N_EMBD;
    f32x4 accA[4][2] = {};
    f32x4 accB[4][2] = {};
    const int NT = K >> 5;

    auto stage = [&](int buf, int k0) {
#pragma unroll
        for (int c = 0; c < 2; c++) {
            const int slot = c * 256 + tid;
            const int r2 = slot >> 3;
            const int w16u = (slot & 7) ^ (r2 & 7);
            const int grow = (w16u >> 2) * 64 + r2;
            const int kc = w16u & 3;
            gload16(A + (size_t)(m0 + grow) * K + k0 + kc * 8, (char*)&As[buf][0] + slot * 16);
        }
        {
            const int slot = tid;
            const int r2 = slot >> 3;
            const int w16u = (slot & 7) ^ (r2 & 7);
            const int grow = (w16u >> 2) * 32 + r2;
            const int kc = w16u & 3;
            gload16(Bw + (size_t)(n0 + grow) * K + k0 + kc * 8, (char*)&Bws[buf][0] + slot * 16);
            gload16(Bv + (size_t)(n0 + grow) * K + k0 + kc * 8, (char*)&Bvs[buf][0] + slot * 16);
        }
    };

    stage(0, 0);
    __syncthreads();
    int cur = 0;
    for (int t = 0; t < NT; t++) {
        if (t + 1 < NT) stage(cur ^ 1, (t + 1) << 5);
        bf16x8 af[4], bwf[2], bvf[2];
#pragma unroll
        for (int q4 = 0; q4 < 4; q4++) {
            const int ga = wm * 64 + q4 * 16 + l15;
            const int ra = ga & 63, ha = ga >> 6;
            af[q4] = *(const bf16x8*)((const char*)&As[cur][0] + ra * 128 + (((ha << 2) | l4) ^ (ra & 7)) * 16);
        }
#pragma unroll
        for (int u = 0; u < 2; u++) {
            const int gb = wn * 32 + u * 16 + l15;
            const int rb = gb & 31, hb = gb >> 5;
            const int off = rb * 128 + (((hb << 2) | l4) ^ (rb & 7)) * 16;
            bwf[u] = *(const bf16x8*)((const char*)&Bws[cur][0] + off);
            bvf[u] = *(const bf16x8*)((const char*)&Bvs[cur][0] + off);
        }
#pragma unroll
        for (int mt = 0; mt < 4; mt++)
#pragma unroll
            for (int u = 0; u < 2; u++) {
                accA[mt][u] = __builtin_amdgcn_mfma_f32_16x16x32_bf16(af[mt], bwf[u], accA[mt][u], 0, 0, 0);
                accB[mt][u] = __builtin_amdgcn_mfma_f32_16x16x32_bf16(af[mt], bvf[u], accB[mt][u], 0, 0, 0);
            }
        __syncthreads();
        cur ^= 1;
    }
#pragma unroll
    for (int mt = 0; mt < 4; mt++) {
#pragma unroll
        for (int u = 0; u < 2; u++) {
            const int n = n0 + wn * 32 + u * 16 + l15;
            const float wbi = wb[n], vbi = vb[n];
#pragma unroll
            for (int r = 0; r < 4; r++) {
                const int m = m0 + wm * 64 + mt * 16 + l4 * 4 + r;
                const float a  = accA[mt][u][r] + wbi;
                const float bb = accB[mt][u][r] + vbi;
                G[(size_t)m * HIDDEN + n] = f2bf(a / (1.f + __expf(-a)) * bb);
            }
        }
    }
}

// ================= MFMA flash attention: single 16KB buffer, 8 blocks/CU (max occupancy) =======
// Inter-block TLP replaces the double-buffer's intra-block overlap (occupancy was the only
// lever that ever moved this kernel: r6 split-KV, r9 LDS halving).
__global__ __launch_bounds__(256, 8) void attn_mfma(const u16* __restrict__ q, const u16* __restrict__ k,
                                                    const u16* __restrict__ vt, u16* __restrict__ o)
{
    __shared__ __align__(16) u16 Kb[64 * 64];   // [ks 64][d 64], 128B rows, swz ^((row&7)<<4)
    __shared__ __align__(16) u16 Vb[64 * 64];   // [d 64][ks 64], 128B rows, same swz
    __shared__ float ml[2][32];
    const int tid = threadIdx.x, l = tid & 63, l31 = l & 31, hh2 = (l >> 5) & 1;
    const int wid  = tid >> 6;
    const int qsub = wid >> 1;
    const int par  = wid & 1;
    const int bh  = blockIdx.x;
    const int qtb = (int)gridDim.y - 1 - (int)blockIdx.y;   // big tiles first
    const int qt  = qtb * 2 + qsub;
    const int qw0 = qt * 32;
    const int nc  = qtb + 1;
    const u16* qb  = q  + (size_t)bh * T_SEQ * HEAD_SIZE;
    const u16* kbg = k  + (size_t)bh * T_SEQ * HEAD_SIZE;
    const u16* vbg = vt + (size_t)bh * HEAD_SIZE * T_SEQ;

    bf16x8 qf[4];
    {
        const u16* qr = qb + (size_t)(qw0 + l31) * HEAD_SIZE + hh2 * 8;
#pragma unroll
        for (int kk = 0; kk < 4; kk++) qf[kk] = *(const bf16x8*)(qr + kk * 16);
    }

    f32x16 oacc0 = {}, oacc1 = {};
    float lrow = 0.f;
    const float M0 = 20.f;                          // fixed exp2-domain offset (Q pre-scaled by qs)

    auto stage = [&](int s0) {
#pragma unroll
        for (int c = 0; c < 2; c++) {
            const int slot = c * 256 + tid;
            const int row = slot >> 3;
            const int sw = ((slot & 7) * 16) ^ ((row & 7) << 4);
            gload16((const char*)(kbg + (size_t)(s0 + row) * HEAD_SIZE) + sw, (char*)&Kb[0] + slot * 16);
        }
#pragma unroll
        for (int c = 0; c < 2; c++) {
            const int slot = c * 256 + tid;
            const int row = slot >> 3;
            const int sw = ((slot & 7) * 16) ^ ((row & 7) << 4);
            gload16((const char*)(vbg + (size_t)row * T_SEQ + s0) + sw, (char*)&Vb[0] + slot * 16);
        }
    };

    for (int j = 0; j < nc; j++) {
        if (j) __syncthreads();            // previous chunk's reads complete before overwrite
        stage(j * 64);
        __syncthreads();                   // drains vmcnt: staged data visible

        const int hc = 2 * j + par;
        if (hc <= qt) {
            // S·qs − M0 directly: C-init = −M0, Q pre-scaled
            f32x16 sa;
#pragma unroll
            for (int reg = 0; reg < 16; reg++) sa[reg] = -M0;
            const int row = par * 32 + l31;
            const int swz = (row & 7) << 4;
#pragma unroll
            for (int kk = 0; kk < 4; kk++) {
                const bf16x8 kf = *(const bf16x8*)((const char*)&Kb[0] + row * 128 + ((kk * 32 + hh2 * 16) ^ swz));
                sa = __builtin_amdgcn_mfma_f32_32x32x16_bf16(kf, qf[kk], sa, 0, 0, 0);
            }
            if (hc == qt) {
#pragma unroll
                for (int reg = 0; reg < 16; reg++) {
                    const int R = (reg & 3) + 8 * (reg >> 2) + 4 * hh2;
                    if (R > l31) sa[reg] = -1e30f;
                }
            }
            // P = exp2(sa); l-sum on VALU (keeps VGPR <= 64 for 8 waves/SIMD)
            float ls = 0.f;
#pragma unroll
            for (int reg = 0; reg < 16; reg++) {
                const float pv = exp2f(sa[reg]);
                sa[reg] = pv;
                ls += pv;
            }
            ls += __shfl_xor(ls, 32);
            lrow += ls;

            unsigned pk[8];
#pragma unroll
            for (int jj = 0; jj < 8; jj++) pk[jj] = cvtpk_bf16(sa[2 * jj], sa[2 * jj + 1]);

#pragma unroll
            for (int st = 0; st < 2; st++) {
                const int b = st * 4;
                union { unsigned u[4]; bf16x8 v; } r;
                const unsigned s0w = (unsigned)__shfl_xor((int)pk[b + 0], 32);
                const unsigned s1w = (unsigned)__shfl_xor((int)pk[b + 1], 32);
                const unsigned s2w = (unsigned)__shfl_xor((int)pk[b + 2], 32);
                const unsigned s3w = (unsigned)__shfl_xor((int)pk[b + 3], 32);
                r.u[0] = hh2 ? s2w : pk[b + 0];
                r.u[1] = hh2 ? s3w : pk[b + 1];
                r.u[2] = hh2 ? pk[b + 2] : s0w;
                r.u[3] = hh2 ? pk[b + 3] : s1w;
#pragma unroll
                for (int dt = 0; dt < 2; dt++) {
                    const int vrow = dt * 32 + l31;
                    const int vswz = (vrow & 7) << 4;
                    const int vcol = (par * 64 + st * 32 + hh2 * 16) ^ vswz;
                    const bf16x8 vf = *(const bf16x8*)((const char*)&Vb[0] + vrow * 128 + vcol);
                    if (dt == 0) oacc0 = __builtin_amdgcn_mfma_f32_32x32x16_bf16(vf, r.v, oacc0, 0, 0, 0);
                    else         oacc1 = __builtin_amdgcn_mfma_f32_32x32x16_bf16(vf, r.v, oacc1, 0, 0, 0);
                }
            }
        }
    }

    // ================= cross-parity merge: O = (O0+O1)/(l0+l1) =================
    __syncthreads();
    float* obuf = qsub ? (float*)&Vb[0] : (float*)&Kb[0];   // 8KB each = [64 d][32 q] f32
    if (par == 1) {
#pragma unroll
        for (int reg = 0; reg < 16; reg++) {
            const int R = (reg & 3) + 8 * (reg >> 2) + 4 * hh2;
            obuf[R * 32 + l31] = oacc0[reg];
            obuf[(32 + R) * 32 + l31] = oacc1[reg];
        }
        if (hh2 == 0) ml[qsub][l31] = lrow;
    }
    __syncthreads();
    if (par == 0) {
        const float inv = 1.f / (lrow + ml[qsub][l31]);
        const int bI = bh >> 4, hd = bh & 15;
        u16* ob = o + ((size_t)(bI * T_SEQ + qw0 + l31)) * N_EMBD + hd * HEAD_SIZE;
#pragma unroll
        for (int g = 0; g < 4; g++) {
            const int d0a = g * 8 + hh2 * 4;
            float v0[4], v1[4];
#pragma unroll
            for (int r = 0; r < 4; r++) {
                const int R = d0a + r;
                v0[r] = (oacc0[4 * g + r] + obuf[R * 32 + l31]) * inv;
                v1[r] = (oacc1[4 * g + r] + obuf[(32 + R) * 32 + l31]) * inv;
            }
            *(ushort4*)(ob + d0a)      = make_ushort4(f2bf(v0[0]), f2bf(v0[1]), f2bf(v0[2]), f2bf(v0[3]));
            *(ushort4*)(ob + 32 + d0a) = make_ushort4(f2bf(v1[0]), f2bf(v1[1]), f2bf(v1[2]), f2bf(v1[3]));
        }
    }
}

extern "C" void kernel_launch(void* const* d_in, const int* in_sizes, int n_in,
                              void* d_out, int out_size, void* d_ws, size_t ws_size,
                              hipStream_t stream)
{
    (void)in_sizes; (void)n_in; (void)out_size; (void)ws_size;
    const float* x      = (const float*)d_in[0];
    const float* ln1_w  = (const float*)d_in[1];
    const float* ln1_b  = (const float*)d_in[2];
    const float* ln2_w  = (const float*)d_in[3];
    const float* ln2_b  = (const float*)d_in[4];
    const float* Wq     = (const float*)d_in[5];
    const float* Wk     = (const float*)d_in[6];
    const float* Wv     = (const float*)d_in[7];
    const float* proj_w = (const float*)d_in[8];
    const float* proj_b = (const float*)d_in[9];
    const float* w_w    = (const float*)d_in[10];
    const float* w_b    = (const float*)d_in[11];
    const float* v_w    = (const float*)d_in[12];
    const float* v_b    = (const float*)d_in[13];
    const float* p_w    = (const float*)d_in[14];
    const float* p_b    = (const float*)d_in[15];
    float* out = (float*)d_out;

    char* W = (char*)d_ws;
    u16*   Wqkv = (u16*)(W + 0);          // [3072][1024] bf16, 6 MB
    u16*   pwT  = (u16*)(W + 6291456);    // [1024][1024], 2 MB
    u16*   wwT  = (u16*)(W + 8388608);    // [2048][1024], 4 MB
    u16*   vvT  = (u16*)(W + 12582912);   // [2048][1024], 4 MB
    u16*   ppT  = (u16*)(W + 16777216);   // [1024][2048], 4 MB
    u16*   h    = (u16*)(W + 20971520);   // [4096][1024] bf16 (LN1 out, later LN2 out)
    u16*   qB   = (u16*)(W + 29360128);   // [B,H,T,D] bf16
    u16*   kB   = (u16*)(W + 37748736);   // [B,H,T,D] bf16
    u16*   vtB  = (u16*)(W + 46137344);   // [B,H,D,T] bf16
    u16*   oB   = (u16*)(W + 54525952);   // [4096][1024] bf16
    float* x1   = (float*)(W + 62914560); // [4096][1024] f32 (ends at 76 MB)
    u16*   ga   = qB;                     // [4096][2048] bf16 over q+k (dead after attn)

    // weight prep (transpose + bf16 cast) — single fused launch
    wtrans_all<<<2560, 256, 0, stream>>>(Wq, Wk, Wv, w_w, v_w, proj_w, p_w,
                                         Wqkv, wwT, vvT, pwT, ppT);

    // 1. LN1 -> h (bf16)
    ln_kernel<<<ROWS, 256, 0, stream>>>(x, ln1_w, ln1_b, h);
    // 2. QKV GEMM -> q,k [B,H,T,D], vt [B,H,D,T]
    gemm_qkv<<<dim3(24, 32), 256, 0, stream>>>(h, Wqkv, qB, kB, vtB);
    // 3. RoPE on q,k (q pre-scaled by qs)
    rope_kernel<<<(BATCH * N_HEAD * T_SEQ * 32) / 256, 256, 0, stream>>>(qB, kB);
    // 4. attention -> o [B,T,C] bf16
    attn_mfma<<<dim3(BATCH * N_HEAD, T_SEQ / 64), 256, 0, stream>>>(qB, kB, vtB, oB);
    // 5. proj + bias + residual(x) -> x1 (f32)
    gemm_br<<<dim3(16, 32), 256, 0, stream>>>(oB, pwT, proj_b, x, x1, N_EMBD, N_EMBD);
    // 6. LN2 -> h (bf16, reused)
    ln_kernel<<<ROWS, 256, 0, stream>>>(x1, ln2_w, ln2_b, h);
    // 7. fused GLU -> ga (bf16)
    gemm_glu<<<dim3(32, 32), 256, 0, stream>>>(h, wwT, vvT, w_b, v_b, ga);
    // 8. final: out = ga·p_w + p_b + x1 (f32)
    gemm_br<<<dim3(16, 32), 256, 0, stream>>>(ga, ppT, p_b, x1, out, N_EMBD, HIDDEN);
}

// Round 17
// 200.256 us; speedup vs baseline: 1.8048x; 1.8048x over previous
//
#include <hip/hip_runtime.h>
#include <math.h>

#define N_EMBD    1024
#define N_HEAD    16
#define HEAD_SIZE 64
#define T_SEQ     2048
#define BATCH     2
#define HIDDEN    2048
#define ROWS      4096

typedef __attribute__((ext_vector_type(8))) short bf16x8;
typedef __attribute__((ext_vector_type(4))) float f32x4;
typedef __attribute__((ext_vector_type(16))) float f32x16;
typedef unsigned short u16;

__device__ __forceinline__ u16 f2bf(float x) {
    union { float f; unsigned u; } v; v.f = x;
    unsigned r = v.u + 0x7fffu + ((v.u >> 16) & 1u);
    return (u16)(r >> 16);
}
__device__ __forceinline__ float bf2f(u16 h) {
    union { unsigned u; float f; } v; v.u = ((unsigned)h) << 16;
    return v.f;
}
__device__ __forceinline__ unsigned cvtpk_bf16(float lo, float hi) {
    unsigned r;
    asm volatile("v_cvt_pk_bf16_f32 %0, %1, %2" : "=v"(r) : "v"(lo), "v"(hi));
    return r;
}
__device__ __forceinline__ void gload16(const void* g, void* lds) {
    __builtin_amdgcn_global_load_lds((const __attribute__((address_space(1))) void*)g,
                                     (__attribute__((address_space(3))) void*)lds, 16, 0, 0);
}

// ================= weight transpose + bf16 cast (single fused kernel) =================
__device__ __forceinline__ void wtrans_body(const float* s, u16* d, int ldS, int ldD,
                                            int k0, int n0, float Ts[64][65])
{
    const int tid = threadIdx.x;
    const int rr = tid >> 4, c4 = (tid & 15) * 4;
#pragma unroll
    for (int i = 0; i < 4; i++) {
        float4 v = *(const float4*)(s + (size_t)(k0 + rr + i * 16) * ldS + n0 + c4);
        Ts[rr + i * 16][c4 + 0] = v.x;
        Ts[rr + i * 16][c4 + 1] = v.y;
        Ts[rr + i * 16][c4 + 2] = v.z;
        Ts[rr + i * 16][c4 + 3] = v.w;
    }
    __syncthreads();
    const int nr = tid >> 2, kc = (tid & 3) * 16;
#pragma unroll
    for (int j = 0; j < 4; j++) {
        u16 t0 = f2bf(Ts[kc + j * 4 + 0][nr]);
        u16 t1 = f2bf(Ts[kc + j * 4 + 1][nr]);
        u16 t2 = f2bf(Ts[kc + j * 4 + 2][nr]);
        u16 t3 = f2bf(Ts[kc + j * 4 + 3][nr]);
        *(ushort4*)(d + (size_t)(n0 + nr) * ldD + k0 + kc + j * 4) = make_ushort4(t0, t1, t2, t3);
    }
}

// linear blocks: [0,768) qkv heads; [768,1792) w_w/v_w; [1792,2048) proj; [2048,2560) p_w
__global__ __launch_bounds__(256) void wtrans_all(const float* __restrict__ Wq, const float* __restrict__ Wk,
                                                  const float* __restrict__ Wv, const float* __restrict__ ww,
                                                  const float* __restrict__ vv, const float* __restrict__ pw,
                                                  const float* __restrict__ ppw,
                                                  u16* __restrict__ Wqkv, u16* __restrict__ wwT,
                                                  u16* __restrict__ vvT, u16* __restrict__ pwT,
                                                  u16* __restrict__ ppT)
{
    __shared__ float Ts[64][65];
    const int b = blockIdx.x;
    const float* s; u16* d; int ldS, ldD, k0, n0;
    if (b < 768) {
        const int z = b >> 4;
        k0 = (b & 15) * 64; n0 = 0;
        const int which = z >> 4;
        s = (which == 0 ? Wq : which == 1 ? Wk : Wv) + (size_t)(z & 15) * 65536;
        d = Wqkv + (size_t)z * 65536;
        ldS = 64; ldD = 1024;
    } else if (b < 1792) {
        const int b2 = b - 768, z = b2 >> 4;
        k0 = (b2 & 15) * 64; n0 = (z & 31) * 64;
        s = (z >> 5) ? vv : ww; d = (z >> 5) ? vvT : wwT;
        ldS = 2048; ldD = 1024;
    } else if (b < 2048) {
        const int b3 = b - 1792;
        k0 = (b3 & 15) * 64; n0 = (b3 >> 4) * 64;
        s = pw; d = pwT; ldS = 1024; ldD = 1024;
    } else {
        const int b4 = b - 2048;
        k0 = (b4 & 31) * 64; n0 = (b4 >> 5) * 64;
        s = ppw; d = ppT; ldS = 1024; ldD = 2048;
    }
    wtrans_body(s, d, ldS, ldD, k0, n0, Ts);
}

// ================= LayerNorm f32 -> bf16 =================
__global__ __launch_bounds__(256) void ln_kernel(const float* __restrict__ x,
                                                 const float* __restrict__ w,
                                                 const float* __restrict__ b,
                                                 u16* __restrict__ out)
{
    const int row = blockIdx.x;
    const int tid = threadIdx.x;
    const float* xr = x + (size_t)row * N_EMBD;
    float4 v = *(const float4*)(xr + tid * 4);
    float s  = v.x + v.y + v.z + v.w;
    float s2 = v.x*v.x + v.y*v.y + v.z*v.z + v.w*v.w;
#pragma unroll
    for (int off = 32; off; off >>= 1) {
        s  += __shfl_xor(s, off);
        s2 += __shfl_xor(s2, off);
    }
    __shared__ float ss[4], ss2[4];
    if ((tid & 63) == 0) { ss[tid >> 6] = s; ss2[tid >> 6] = s2; }
    __syncthreads();
    s  = ss[0] + ss[1] + ss[2] + ss[3];
    s2 = ss2[0] + ss2[1] + ss2[2] + ss2[3];
    const float mean = s * (1.0f / N_EMBD);
    const float var  = s2 * (1.0f / N_EMBD) - mean * mean;
    const float rstd = rsqrtf(var + 1e-5f);
    float4 wv = *(const float4*)(w + tid * 4);
    float4 bv = *(const float4*)(b + tid * 4);
    ushort4 st = make_ushort4(f2bf((v.x - mean) * rstd * wv.x + bv.x),
                              f2bf((v.y - mean) * rstd * wv.y + bv.y),
                              f2bf((v.z - mean) * rstd * wv.z + bv.z),
                              f2bf((v.w - mean) * rstd * wv.w + bv.w));
    *(ushort4*)(out + (size_t)row * N_EMBD + tid * 4) = st;
}

// ================= RoPE on bf16 q,k; q additionally pre-scaled by qs = log2(e)/8 =================
__global__ __launch_bounds__(256) void rope_kernel(u16* __restrict__ q, u16* __restrict__ k)
{
    const int u = blockIdx.x * 256 + threadIdx.x;
    const int i  = u & 31;
    const int t  = (u >> 5) & (T_SEQ - 1);
    const int bh = u >> 16;
    const size_t base = ((size_t)bh * T_SEQ + t) * HEAD_SIZE + 2 * i;
    const float L = 0.28782313662425572f;   // ln(10000)/32
    const float QS = 0.125f * 1.44269504088896f;   // 1/sqrt(64) * log2(e)
    const int i0 = (2 * i) & 31, i1 = (2 * i + 1) & 31;
    float c0, s0, c1, s1;
    sincosf((float)t * __expf(-(float)i0 * L), &s0, &c0);
    sincosf((float)t * __expf(-(float)i1 * L), &s1, &c1);
    float a0 = bf2f(q[base]), a1 = bf2f(q[base + 1]);
    q[base]     = f2bf((a0 * c0 - a1 * s0) * QS);
    q[base + 1] = f2bf((a1 * c1 + a0 * s1) * QS);
    float b0 = bf2f(k[base]), b1 = bf2f(k[base + 1]);
    k[base]     = f2bf(b0 * c0 - b1 * s0);
    k[base + 1] = f2bf(b1 * c1 + b0 * s1);
}

// ================= MFMA GEMM (128x64 tile, BK=64 swizzled, 2-phase dbuf) — r12-measured best ====
__global__ __launch_bounds__(256) void gemm_br(const u16* __restrict__ A, const u16* __restrict__ Bt,
                                               const float* __restrict__ bias, const float* __restrict__ resid,
                                               float* __restrict__ Cf,
                                               int N, int K)
{
    __shared__ __align__(16) u16 As[2][128 * 64];
    __shared__ __align__(16) u16 Bs[2][64 * 64];
    const int tid = threadIdx.x, w = tid >> 6, l = tid & 63, l15 = l & 15, l4 = l >> 4;
    const int wm = w >> 1, wn = w & 1;
    const int n0 = blockIdx.x * 64, m0 = blockIdx.y * 128;
    f32x4 acc[4][2] = {};
    const int NT = K >> 6;

    auto stage = [&](int buf, int k0) {
#pragma unroll
        for (int c = 0; c < 4; c++) {
            const int slot = c * 256 + tid;
            const int row = slot >> 3;
            const int sw = ((slot & 7) * 16) ^ ((row & 7) << 4);
            gload16((const char*)(A + (size_t)(m0 + row) * K + k0) + sw, (char*)&As[buf][0] + slot * 16);
        }
#pragma unroll
        for (int c = 0; c < 2; c++) {
            const int slot = c * 256 + tid;
            const int row = slot >> 3;
            const int sw = ((slot & 7) * 16) ^ ((row & 7) << 4);
            gload16((const char*)(Bt + (size_t)(n0 + row) * K + k0) + sw, (char*)&Bs[buf][0] + slot * 16);
        }
    };

    stage(0, 0);
    __syncthreads();
    int cur = 0;
    for (int t = 0; t < NT; t++) {
        if (t + 1 < NT) stage(cur ^ 1, (t + 1) << 6);
#pragma unroll
        for (int ks = 0; ks < 2; ks++) {
            const int cb = ks * 64 + l4 * 16;
            bf16x8 af[4], bf[2];
#pragma unroll
            for (int mt = 0; mt < 4; mt++) {
                const int row = wm * 64 + mt * 16 + l15;
                af[mt] = *(const bf16x8*)((const char*)&As[cur][0] + row * 128 + (cb ^ ((row & 7) << 4)));
            }
#pragma unroll
            for (int u = 0; u < 2; u++) {
                const int row = wn * 32 + u * 16 + l15;
                bf[u] = *(const bf16x8*)((const char*)&Bs[cur][0] + row * 128 + (cb ^ ((row & 7) << 4)));
            }
#pragma unroll
            for (int mt = 0; mt < 4; mt++)
#pragma unroll
                for (int u = 0; u < 2; u++)
                    acc[mt][u] = __builtin_amdgcn_mfma_f32_16x16x32_bf16(af[mt], bf[u], acc[mt][u], 0, 0, 0);
        }
        __syncthreads();
        cur ^= 1;
    }
#pragma unroll
    for (int mt = 0; mt < 4; mt++) {
#pragma unroll
        for (int u = 0; u < 2; u++) {
            const int n = n0 + wn * 32 + u * 16 + l15;
            const float bi = bias[n];
#pragma unroll
            for (int r = 0; r < 4; r++) {
                const int m = m0 + wm * 64 + mt * 16 + l4 * 4 + r;
                const size_t idx = (size_t)m * N + n;
                Cf[idx] = acc[mt][u][r] + bi + resid[idx];
            }
        }
    }
}

// ================= QKV GEMM (128x128, packed BK=32, 2-phase dbuf) =================
__global__ __launch_bounds__(256, 4) void gemm_qkv(const u16* __restrict__ A, const u16* __restrict__ Bt,
                                                   u16* __restrict__ qo, u16* __restrict__ ko, u16* __restrict__ vto)
{
    __shared__ __align__(16) u16 As[2][64 * 64];   // packed [64][128B]
    __shared__ __align__(16) u16 Bs[2][64 * 64];
    const int tid = threadIdx.x, w = tid >> 6, l = tid & 63, l15 = l & 15, l4 = l >> 4;
    const int wm = w >> 1, wn = w & 1;
    const int n0 = blockIdx.x * 128, m0 = blockIdx.y * 128;
    const int K = N_EMBD;
    f32x4 acc[4][4] = {};
    const int NT = K >> 5;

    auto stage = [&](int buf, int k0) {
#pragma unroll
        for (int c = 0; c < 2; c++) {
            const int slot = c * 256 + tid;
            const int r2 = slot >> 3;
            const int w16u = (slot & 7) ^ (r2 & 7);
            const int grow = (w16u >> 2) * 64 + r2;
            const int kc = w16u & 3;
            gload16(A  + (size_t)(m0 + grow) * K + k0 + kc * 8, (char*)&As[buf][0] + slot * 16);
            gload16(Bt + (size_t)(n0 + grow) * K + k0 + kc * 8, (char*)&Bs[buf][0] + slot * 16);
        }
    };

    stage(0, 0);
    __syncthreads();
    int cur = 0;
    for (int t = 0; t < NT; t++) {
        if (t + 1 < NT) stage(cur ^ 1, (t + 1) << 5);
        bf16x8 af[4], bf[4];
#pragma unroll
        for (int q4 = 0; q4 < 4; q4++) {
            const int ga = wm * 64 + q4 * 16 + l15;
            const int ra = ga & 63, ha = ga >> 6;
            af[q4] = *(const bf16x8*)((const char*)&As[cur][0] + ra * 128 + (((ha << 2) | l4) ^ (ra & 7)) * 16);
            const int gb = wn * 64 + q4 * 16 + l15;
            const int rb = gb & 63, hb = gb >> 6;
            bf[q4] = *(const bf16x8*)((const char*)&Bs[cur][0] + rb * 128 + (((hb << 2) | l4) ^ (rb & 7)) * 16);
        }
#pragma unroll
        for (int mt = 0; mt < 4; mt++)
#pragma unroll
            for (int nt = 0; nt < 4; nt++)
                acc[mt][nt] = __builtin_amdgcn_mfma_f32_16x16x32_bf16(af[mt], bf[nt], acc[mt][nt], 0, 0, 0);
        __syncthreads();
        cur ^= 1;
    }
#pragma unroll
    for (int mt = 0; mt < 4; mt++) {
#pragma unroll
        for (int nt = 0; nt < 4; nt++) {
            const int n = n0 + wn * 64 + nt * 16 + l15;
            const int which = n >> 10, hd = (n >> 6) & 15, dd = n & 63;
            const int mb = m0 + wm * 64 + mt * 16 + l4 * 4;
            const int bI = mb >> 11, tq = mb & (T_SEQ - 1);
            if (which == 2) {
                ushort4 st = make_ushort4(f2bf(acc[mt][nt][0]), f2bf(acc[mt][nt][1]),
                                          f2bf(acc[mt][nt][2]), f2bf(acc[mt][nt][3]));
                *(ushort4*)(vto + ((size_t)(bI * N_HEAD + hd) * HEAD_SIZE + dd) * T_SEQ + tq) = st;
            } else {
                u16* dst = (which == 0) ? qo : ko;
#pragma unroll
                for (int r = 0; r < 4; r++)
                    dst[((size_t)(bI * N_HEAD + hd) * T_SEQ + tq + r) * HEAD_SIZE + dd] = f2bf(acc[mt][nt][r]);
            }
        }
    }
}

// ================= Fused dual-GEMM GLU (128x64, packed BK=32, 4 blocks/CU) =================
__global__ __launch_bounds__(256, 4) void gemm_glu(const u16* __restrict__ A, const u16* __restrict__ Bw,
                                                   const u16* __restrict__ Bv,
                                                   const float* __restrict__ wb, const float* __restrict__ vb,
                                                   u16* __restrict__ G)
{
    __shared__ __align__(16) u16 As[2][64 * 64];
    __shared__ __align__(16) u16 Bws[2][32 * 64];
    __shared__ __align__(16) u16 Bvs[2][32 * 64];
    const int tid = threadIdx.x, w = tid >> 6, l = tid & 63, l15 = l & 15, l4 = l >> 4;
    const int wm = w >> 1, wn = w & 1;
    const int n0 = blockIdx.x * 64, m0 = blockIdx.y * 128;
    const int K = N_EMBD;
    f32x4 accA[4][2] = {};
    f32x4 accB[4][2] = {};
    const int NT = K >> 5;

    auto stage = [&](int buf, int k0) {
#pragma unroll
        for (int c = 0; c < 2; c++) {
            const int slot = c * 256 + tid;
            const int r2 = slot >> 3;
            const int w16u = (slot & 7) ^ (r2 & 7);
            const int grow = (w16u >> 2) * 64 + r2;
            const int kc = w16u & 3;
            gload16(A + (size_t)(m0 + grow) * K + k0 + kc * 8, (char*)&As[buf][0] + slot * 16);
        }
        {
            const int slot = tid;
            const int r2 = slot >> 3;
            const int w16u = (slot & 7) ^ (r2 & 7);
            const int grow = (w16u >> 2) * 32 + r2;
            const int kc = w16u & 3;
            gload16(Bw + (size_t)(n0 + grow) * K + k0 + kc * 8, (char*)&Bws[buf][0] + slot * 16);
            gload16(Bv + (size_t)(n0 + grow) * K + k0 + kc * 8, (char*)&Bvs[buf][0] + slot * 16);
        }
    };

    stage(0, 0);
    __syncthreads();
    int cur = 0;
    for (int t = 0; t < NT; t++) {
        if (t + 1 < NT) stage(cur ^ 1, (t + 1) << 5);
        bf16x8 af[4], bwf[2], bvf[2];
#pragma unroll
        for (int q4 = 0; q4 < 4; q4++) {
            const int ga = wm * 64 + q4 * 16 + l15;
            const int ra = ga & 63, ha = ga >> 6;
            af[q4] = *(const bf16x8*)((const char*)&As[cur][0] + ra * 128 + (((ha << 2) | l4) ^ (ra & 7)) * 16);
        }
#pragma unroll
        for (int u = 0; u < 2; u++) {
            const int gb = wn * 32 + u * 16 + l15;
            const int rb = gb & 31, hb = gb >> 5;
            const int off = rb * 128 + (((hb << 2) | l4) ^ (rb & 7)) * 16;
            bwf[u] = *(const bf16x8*)((const char*)&Bws[cur][0] + off);
            bvf[u] = *(const bf16x8*)((const char*)&Bvs[cur][0] + off);
        }
#pragma unroll
        for (int mt = 0; mt < 4; mt++)
#pragma unroll
            for (int u = 0; u < 2; u++) {
                accA[mt][u] = __builtin_amdgcn_mfma_f32_16x16x32_bf16(af[mt], bwf[u], accA[mt][u], 0, 0, 0);
                accB[mt][u] = __builtin_amdgcn_mfma_f32_16x16x32_bf16(af[mt], bvf[u], accB[mt][u], 0, 0, 0);
            }
        __syncthreads();
        cur ^= 1;
    }
#pragma unroll
    for (int mt = 0; mt < 4; mt++) {
#pragma unroll
        for (int u = 0; u < 2; u++) {
            const int n = n0 + wn * 32 + u * 16 + l15;
            const float wbi = wb[n], vbi = vb[n];
#pragma unroll
            for (int r = 0; r < 4; r++) {
                const int m = m0 + wm * 64 + mt * 16 + l4 * 4 + r;
                const float a  = accA[mt][u][r] + wbi;
                const float bb = accB[mt][u][r] + vbi;
                G[(size_t)m * HIDDEN + n] = f2bf(a / (1.f + __expf(-a)) * bb);
            }
        }
    }
}

// ================= MFMA flash attention: 64-ks chunks, 32-ks parity halves, 4 blocks/CU =========
__global__ __launch_bounds__(256, 4) void attn_mfma(const u16* __restrict__ q, const u16* __restrict__ k,
                                                    const u16* __restrict__ vt, u16* __restrict__ o)
{
    __shared__ __align__(16) u16 Kb[2][64 * 64];   // [ks 64][d 64], 128B rows, swz ^((row&7)<<4)
    __shared__ __align__(16) u16 Vb[2][64 * 64];   // [d 64][ks 64], 128B rows, same swz
    __shared__ float ml[2][32];
    const int tid = threadIdx.x, l = tid & 63, l31 = l & 31, hh2 = (l >> 5) & 1;
    const int wid  = tid >> 6;
    const int qsub = wid >> 1;
    const int par  = wid & 1;
    const int bh  = blockIdx.x;
    const int qtb = (int)gridDim.y - 1 - (int)blockIdx.y;   // big tiles first (r12-measured best)
    const int qt  = qtb * 2 + qsub;
    const int qw0 = qt * 32;
    const int nc  = qtb + 1;
    const u16* qb  = q  + (size_t)bh * T_SEQ * HEAD_SIZE;
    const u16* kbg = k  + (size_t)bh * T_SEQ * HEAD_SIZE;
    const u16* vbg = vt + (size_t)bh * HEAD_SIZE * T_SEQ;

    bf16x8 qf[4];
    {
        const u16* qr = qb + (size_t)(qw0 + l31) * HEAD_SIZE + hh2 * 8;
#pragma unroll
        for (int kk = 0; kk < 4; kk++) qf[kk] = *(const bf16x8*)(qr + kk * 16);
    }
    bf16x8 onesf;
#pragma unroll
    for (int e = 0; e < 8; e++) onesf[e] = (short)0x3F80;   // bf16 1.0

    f32x16 oacc0 = {}, oacc1 = {}, lacc = {};
    const float M0 = 20.f;                          // fixed exp2-domain offset

    auto stage = [&](int buf, int s0) {
#pragma unroll
        for (int c = 0; c < 2; c++) {
            const int slot = c * 256 + tid;
            const int row = slot >> 3;
            const int sw = ((slot & 7) * 16) ^ ((row & 7) << 4);
            gload16((const char*)(kbg + (size_t)(s0 + row) * HEAD_SIZE) + sw, (char*)&Kb[buf][0] + slot * 16);
        }
#pragma unroll
        for (int c = 0; c < 2; c++) {
            const int slot = c * 256 + tid;
            const int row = slot >> 3;
            const int sw = ((slot & 7) * 16) ^ ((row & 7) << 4);
            gload16((const char*)(vbg + (size_t)row * T_SEQ + s0) + sw, (char*)&Vb[buf][0] + slot * 16);
        }
    };

    stage(0, 0);
    __syncthreads();
    int cur = 0;

    for (int j = 0; j < nc; j++) {
        if (j + 1 < nc) stage(cur ^ 1, (j + 1) * 64);

        const int hc = 2 * j + par;
        if (hc <= qt) {
            // S·qs − M0 directly: C-init = −M0, Q pre-scaled
            f32x16 sa;
#pragma unroll
            for (int reg = 0; reg < 16; reg++) sa[reg] = -M0;
            const int row = par * 32 + l31;
            const int swz = (row & 7) << 4;
#pragma unroll
            for (int kk = 0; kk < 4; kk++) {
                const bf16x8 kf = *(const bf16x8*)((const char*)&Kb[cur][0] + row * 128 + ((kk * 32 + hh2 * 16) ^ swz));
                sa = __builtin_amdgcn_mfma_f32_32x32x16_bf16(kf, qf[kk], sa, 0, 0, 0);
            }
            if (hc == qt) {
#pragma unroll
                for (int reg = 0; reg < 16; reg++) {
                    const int R = (reg & 3) + 8 * (reg >> 2) + 4 * hh2;
                    if (R > l31) sa[reg] = -1e30f;
                }
            }
            // P = exp2(sa)
#pragma unroll
            for (int reg = 0; reg < 16; reg++) sa[reg] = exp2f(sa[reg]);

            unsigned pk[8];
#pragma unroll
            for (int jj = 0; jj < 8; jj++) pk[jj] = cvtpk_bf16(sa[2 * jj], sa[2 * jj + 1]);

#pragma unroll
            for (int st = 0; st < 2; st++) {
                const int b = st * 4;
                union { unsigned u[4]; bf16x8 v; } r;
                const unsigned s0w = (unsigned)__shfl_xor((int)pk[b + 0], 32);
                const unsigned s1w = (unsigned)__shfl_xor((int)pk[b + 1], 32);
                const unsigned s2w = (unsigned)__shfl_xor((int)pk[b + 2], 32);
                const unsigned s3w = (unsigned)__shfl_xor((int)pk[b + 3], 32);
                r.u[0] = hh2 ? s2w : pk[b + 0];
                r.u[1] = hh2 ? s3w : pk[b + 1];
                r.u[2] = hh2 ? pk[b + 2] : s0w;
                r.u[3] = hh2 ? pk[b + 3] : s1w;
                // l-sum on the MFMA pipe
                lacc = __builtin_amdgcn_mfma_f32_32x32x16_bf16(onesf, r.v, lacc, 0, 0, 0);
#pragma unroll
                for (int dt = 0; dt < 2; dt++) {
                    const int vrow = dt * 32 + l31;
                    const int vswz = (vrow & 7) << 4;
                    const int vcol = (par * 64 + st * 32 + hh2 * 16) ^ vswz;
                    const bf16x8 vf = *(const bf16x8*)((const char*)&Vb[cur][0] + vrow * 128 + vcol);
                    if (dt == 0) oacc0 = __builtin_amdgcn_mfma_f32_32x32x16_bf16(vf, r.v, oacc0, 0, 0, 0);
                    else         oacc1 = __builtin_amdgcn_mfma_f32_32x32x16_bf16(vf, r.v, oacc1, 0, 0, 0);
                }
            }
        }
        __syncthreads();
        cur ^= 1;
    }

    // ================= cross-parity merge: O = (O0+O1)/(l0+l1) =================
    float* obuf = (float*)&Kb[0][0] + (size_t)qsub * 2048;
    if (par == 1) {
#pragma unroll
        for (int reg = 0; reg < 16; reg++) {
            const int R = (reg & 3) + 8 * (reg >> 2) + 4 * hh2;
            obuf[R * 32 + l31] = oacc0[reg];
            obuf[(32 + R) * 32 + l31] = oacc1[reg];
        }
        if (hh2 == 0) ml[qsub][l31] = lacc[0];
    }
    __syncthreads();
    if (par == 0) {
        const float inv = 1.f / (lacc[0] + ml[qsub][l31]);
        const int bI = bh >> 4, hd = bh & 15;
        u16* ob = o + ((size_t)(bI * T_SEQ + qw0 + l31)) * N_EMBD + hd * HEAD_SIZE;
#pragma unroll
        for (int g = 0; g < 4; g++) {
            const int d0a = g * 8 + hh2 * 4;
            float v0[4], v1[4];
#pragma unroll
            for (int r = 0; r < 4; r++) {
                const int R = d0a + r;
                v0[r] = (oacc0[4 * g + r] + obuf[R * 32 + l31]) * inv;
                v1[r] = (oacc1[4 * g + r] + obuf[(32 + R) * 32 + l31]) * inv;
            }
            *(ushort4*)(ob + d0a)      = make_ushort4(f2bf(v0[0]), f2bf(v0[1]), f2bf(v0[2]), f2bf(v0[3]));
            *(ushort4*)(ob + 32 + d0a) = make_ushort4(f2bf(v1[0]), f2bf(v1[1]), f2bf(v1[2]), f2bf(v1[3]));
        }
    }
}

extern "C" void kernel_launch(void* const* d_in, const int* in_sizes, int n_in,
                              void* d_out, int out_size, void* d_ws, size_t ws_size,
                              hipStream_t stream)
{
    (void)in_sizes; (void)n_in; (void)out_size; (void)ws_size;
    const float* x      = (const float*)d_in[0];
    const float* ln1_w  = (const float*)d_in[1];
    const float* ln1_b  = (const float*)d_in[2];
    const float* ln2_w  = (const float*)d_in[3];
    const float* ln2_b  = (const float*)d_in[4];
    const float* Wq     = (const float*)d_in[5];
    const float* Wk     = (const float*)d_in[6];
    const float* Wv     = (const float*)d_in[7];
    const float* proj_w = (const float*)d_in[8];
    const float* proj_b = (const float*)d_in[9];
    const float* w_w    = (const float*)d_in[10];
    const float* w_b    = (const float*)d_in[11];
    const float* v_w    = (const float*)d_in[12];
    const float* v_b    = (const float*)d_in[13];
    const float* p_w    = (const float*)d_in[14];
    const float* p_b    = (const float*)d_in[15];
    float* out = (float*)d_out;

    char* W = (char*)d_ws;
    u16*   Wqkv = (u16*)(W + 0);          // [3072][1024] bf16, 6 MB
    u16*   pwT  = (u16*)(W + 6291456);    // [1024][1024], 2 MB
    u16*   wwT  = (u16*)(W + 8388608);    // [2048][1024], 4 MB
    u16*   vvT  = (u16*)(W + 12582912);   // [2048][1024], 4 MB
    u16*   ppT  = (u16*)(W + 16777216);   // [1024][2048], 4 MB
    u16*   h    = (u16*)(W + 20971520);   // [4096][1024] bf16 (LN1 out, later LN2 out)
    u16*   qB   = (u16*)(W + 29360128);   // [B,H,T,D] bf16
    u16*   kB   = (u16*)(W + 37748736);   // [B,H,T,D] bf16
    u16*   vtB  = (u16*)(W + 46137344);   // [B,H,D,T] bf16
    u16*   oB   = (u16*)(W + 54525952);   // [4096][1024] bf16
    float* x1   = (float*)(W + 62914560); // [4096][1024] f32 (ends at 76 MB)
    u16*   ga   = qB;                     // [4096][2048] bf16 over q+k (dead after attn)

    // weight prep (transpose + bf16 cast) — single fused launch
    wtrans_all<<<2560, 256, 0, stream>>>(Wq, Wk, Wv, w_w, v_w, proj_w, p_w,
                                         Wqkv, wwT, vvT, pwT, ppT);

    // 1. LN1 -> h (bf16)
    ln_kernel<<<ROWS, 256, 0, stream>>>(x, ln1_w, ln1_b, h);
    // 2. QKV GEMM -> q,k [B,H,T,D], vt [B,H,D,T]
    gemm_qkv<<<dim3(24, 32), 256, 0, stream>>>(h, Wqkv, qB, kB, vtB);
    // 3. RoPE on q,k (q pre-scaled by qs)
    rope_kernel<<<(BATCH * N_HEAD * T_SEQ * 32) / 256, 256, 0, stream>>>(qB, kB);
    // 4. attention -> o [B,T,C] bf16
    attn_mfma<<<dim3(BATCH * N_HEAD, T_SEQ / 64), 256, 0, stream>>>(qB, kB, vtB, oB);
    // 5. proj + bias + residual(x) -> x1 (f32)
    gemm_br<<<dim3(16, 32), 256, 0, stream>>>(oB, pwT, proj_b, x, x1, N_EMBD, N_EMBD);
    // 6. LN2 -> h (bf16, reused)
    ln_kernel<<<ROWS, 256, 0, stream>>>(x1, ln2_w, ln2_b, h);
    // 7. fused GLU -> ga (bf16)
    gemm_glu<<<dim3(32, 32), 256, 0, stream>>>(h, wwT, vvT, w_b, v_b, ga);
    // 8. final: out = ga·p_w + p_b + x1 (f32)
    gemm_br<<<dim3(16, 32), 256, 0, stream>>>(ga, ppT, p_b, x1, out, N_EMBD, HIDDEN);
}